// Round 3
// baseline (351.852 us; speedup 1.0000x reference)
//
#include <hip/hip_runtime.h>
#include <cstdint>
#include <cstddef>

#define NPTS   4096
#define BATCH  4
#define KNN    8
#define EPS_F  1e-12f

__device__ __forceinline__ uint32_t u32min(uint32_t a, uint32_t b) { return a < b ? a : b; }
__device__ __forceinline__ uint32_t u32max(uint32_t a, uint32_t b) { return a > b ? a : b; }
__device__ __forceinline__ unsigned long long u64min(unsigned long long a, unsigned long long b) { return a < b ? a : b; }
__device__ __forceinline__ unsigned long long u64max(unsigned long long a, unsigned long long b) { return a > b ? a : b; }

// v_med3_u32: for sorted a<=b, med3(a,b,x) == clamp(x,a,b) — one instruction.
__device__ __forceinline__ uint32_t umed3(uint32_t a, uint32_t b, uint32_t c) {
  uint32_t d;
  asm("v_med3_u32 %0, %1, %2, %3" : "=v"(d) : "v"(a), "v"(b), "v"(c));
  return d;
}

// Insert key into ascending 9-list, dropping the largest: 1 min + 8 med3.
__device__ __forceinline__ void insert9(uint32_t loc[KNN + 1], uint32_t key) {
  uint32_t prev = loc[0];
  loc[0] = u32min(prev, key);
#pragma unroll
  for (int m = 1; m <= KNN; ++m) {
    const uint32_t cur = loc[m];
    loc[m] = umed3(prev, cur, key);
    prev = cur;
  }
}

// Streaming bitonic merge of NC sorted 8-lists, keep smallest 8.
template <int NC>
__device__ __forceinline__ void merge_list(const uint32_t* __restrict__ base, int i,
                                           uint32_t out[KNN]) {
  const uint32_t* p0 = base + (size_t)i * KNN;
  uint4 a = *(const uint4*)p0, bq = *(const uint4*)(p0 + 4);
  out[0] = a.x; out[1] = a.y; out[2] = a.z; out[3] = a.w;
  out[4] = bq.x; out[5] = bq.y; out[6] = bq.z; out[7] = bq.w;
#pragma unroll
  for (int c = 1; c < NC; ++c) {
    const uint32_t* pc = base + ((size_t)c * NPTS + (size_t)i) * KNN;
    const uint4 l0 = *(const uint4*)pc, l1 = *(const uint4*)(pc + 4);
    const uint32_t L[KNN] = {l0.x, l0.y, l0.z, l0.w, l1.x, l1.y, l1.z, l1.w};
    uint32_t t[KNN];
#pragma unroll
    for (int m = 0; m < KNN; ++m) t[m] = u32min(out[m], L[KNN - 1 - m]);
    if (c != NC - 1) {
#define CEU(x, y) { uint32_t lo = u32min(t[x], t[y]); uint32_t hi = u32max(t[x], t[y]); t[x] = lo; t[y] = hi; }
      CEU(0,4) CEU(1,5) CEU(2,6) CEU(3,7)
      CEU(0,2) CEU(1,3) CEU(4,6) CEU(5,7)
      CEU(0,1) CEU(2,3) CEU(4,5) CEU(6,7)
#undef CEU
    }
#pragma unroll
    for (int m = 0; m < KNN; ++m) out[m] = t[m];
  }
}

// Batcher odd-even mergesort, 8 elements, 19 compare-exchanges.
__device__ __forceinline__ void sort8(unsigned long long s[8]) {
#define CE(a, b) { unsigned long long lo = u64min(s[a], s[b]); \
                   unsigned long long hi = u64max(s[a], s[b]); s[a] = lo; s[b] = hi; }
  CE(0,1) CE(2,3) CE(0,2) CE(1,3) CE(1,2)
  CE(4,5) CE(6,7) CE(4,6) CE(5,7) CE(5,6)
  CE(0,4) CE(1,5) CE(2,6) CE(3,7)
  CE(2,4) CE(3,5)
  CE(1,2) CE(3,4) CE(5,6)
#undef CE
}

// Merge + exact-recompute + sort one cloud's kNN for point i.
// Returns sorted neighbor indices in jnb[8], density sum and cov diag/off-diag.
template <int NC>
__device__ __forceinline__ void cloud_knn(const float* __restrict__ C,
                                          const uint32_t* __restrict__ part_base,
                                          int i, float cx, float cy, float cz, float sq,
                                          int jnb[KNN], float& dsum, float cov[6]) {
  uint32_t m[KNN];
  merge_list<NC>(part_base, i, m);
  unsigned long long k8[KNN];
#pragma unroll
  for (int k = 0; k < KNN; ++k) {
    const int j = (int)(m[k] & 0xFFFu);
    const float x = C[3 * j], y = C[3 * j + 1], z = C[3 * j + 2];
    const float d2 = sq + (x * x + y * y + z * z) - 2.0f * (cx * x + cy * y + cz * z);
    const float dist = sqrtf(fmaxf(d2, EPS_F));
    k8[k] = ((unsigned long long)__float_as_uint(dist) << 12) | (unsigned long long)j;
  }
  sort8(k8);
  dsum = 0.f;
#pragma unroll
  for (int k = 0; k < 6; ++k) cov[k] = 0.f;
#pragma unroll
  for (int k = 0; k < KNN; ++k) {
    const int j = (int)(k8[k] & 0xFFFu);
    jnb[k] = j;
    dsum += __uint_as_float((uint32_t)(k8[k] >> 12));
    const float ax = C[3 * j] - cx, ay = C[3 * j + 1] - cy, az = C[3 * j + 2] - cz;
    cov[0] += ax * ax; cov[1] += ay * ay; cov[2] += az * az;
    cov[3] += ax * ay; cov[4] += ax * az; cov[5] += ay * az;
  }
}

// ---------------------------------------------------------------------------
// Single fused kernel: phase 1 = per-(cloud,b,pointgroup,chunk) partial top-8
// with LDS-broadcast candidates; ticket-based completion; last 64 finishers
// each compute one 256-point loss slice; last of those reduces + writes out.
// ---------------------------------------------------------------------------
template <int NC>
__global__ void __launch_bounds__(256, 8)
fused_t(const float* __restrict__ pred, const float* __restrict__ tgt,
        uint32_t* __restrict__ partial, double* __restrict__ sums,
        uint32_t* __restrict__ counters, float* __restrict__ out) {
  constexpr int CHN  = NPTS / NC;
  constexpr int TOTB = 2 * BATCH * (NPTS / 256) * NC;

  __shared__ float4 sc[CHN];
  __shared__ float red[12];
  __shared__ unsigned sbc[2];

  // ---------------- phase 1: kNN partial ----------------
  int bx = blockIdx.x;
  const int chunk = bx % NC; bx /= NC;
  const int ig    = bx & 15; bx >>= 4;
  const int b     = bx & 3;  bx >>= 2;
  const int cloud = bx;
  const float* __restrict__ pts = (cloud ? tgt : pred) + (size_t)b * NPTS * 3;
  const int tid = threadIdx.x;
  const int i = ig * 256 + tid;
  const int j0 = chunk * CHN;

  // Stage chunk into LDS as float4(x,y,z,pad): coalesced read, deswizzled write.
  {
    const float* __restrict__ raw = pts + 3 * j0;
    float* __restrict__ scf = (float*)sc;
    for (int d = tid; d < 3 * CHN; d += 256) {
      const int pq = d / 3;          // magic-mul div by const
      const int c = d - 3 * pq;
      scf[4 * pq + c] = raw[d];
    }
  }
  __syncthreads();

  const float xix = pts[3 * i], xiy = pts[3 * i + 1], xiz = pts[3 * i + 2];
  uint32_t loc[KNN + 1];
#pragma unroll
  for (int k = 0; k <= KNN; ++k) loc[k] = 0xFFFFFFFFu;

#pragma unroll 4
  for (int t = 0; t < CHN; ++t) {
    const float4 q = sc[t];          // uniform address -> broadcast ds_read_b128
    const float dx = xix - q.x, dy = xiy - q.y, dz = xiz - q.z;
    const float d2 = fmaf(dx, dx, fmaf(dy, dy, dz * dz));
    const uint32_t key = (__float_as_uint(d2) & 0xFFFFF000u) | (uint32_t)(j0 + t);
    insert9(loc, key);               // self: d2 == +0 exactly -> rank 0
  }

  const bool self_chunk = ((ig * 256) / CHN) == chunk;
  {
    uint4 o0, o1;
    if (self_chunk) {
      o0 = make_uint4(loc[1], loc[2], loc[3], loc[4]);
      o1 = make_uint4(loc[5], loc[6], loc[7], loc[8]);
    } else {
      o0 = make_uint4(loc[0], loc[1], loc[2], loc[3]);
      o1 = make_uint4(loc[4], loc[5], loc[6], loc[7]);
    }
    uint32_t* pw = partial +
        ((((size_t)(cloud * BATCH + b) * NC + chunk) * NPTS) + (size_t)i) * KNN;
    *(uint4*)pw = o0;
    *(uint4*)(pw + 4) = o1;
  }

  // ---------------- ticket: last 64 finishers do the loss ----------------
  __threadfence();
  __syncthreads();
  if (tid == 0) sbc[0] = atomicAdd(&counters[0], 1u) + 1u;
  __syncthreads();
  const unsigned rank = sbc[0];
  if (rank <= (unsigned)(TOTB - 64)) return;
  const int slice = (int)(rank - (TOTB - 64) - 1);  // 0..63

  if (tid == 0) {  // wait for ALL partials (<=64 spinners << capacity: no deadlock)
    while (__hip_atomic_load(&counters[0], __ATOMIC_RELAXED, __HIP_MEMORY_SCOPE_AGENT)
           < (unsigned)TOTB)
      __builtin_amdgcn_s_sleep(8);
  }
  __syncthreads();
  __threadfence();  // acquire: make remote partials visible

  // ---------------- phase 2: loss for 256 points ----------------
  const int p  = slice * 256 + tid;
  const int pb = p >> 12;
  const int pi = p & (NPTS - 1);
  const float* __restrict__ P = pred + (size_t)pb * NPTS * 3;
  const float* __restrict__ T = tgt  + (size_t)pb * NPTS * 3;

  const float pix = P[3 * pi], piy = P[3 * pi + 1], piz = P[3 * pi + 2];
  const float tix = T[3 * pi], tiy = T[3 * pi + 1], tiz = T[3 * pi + 2];

  int jp[KNN], jt[KNN];
  float dsp, dst, pcov[6], tcov[6];
  cloud_knn<NC>(P, partial + (size_t)(0 * BATCH + pb) * NC * NPTS * KNN, pi,
                pix, piy, piz, pix * pix + piy * piy + piz * piz, jp, dsp, pcov);
  cloud_knn<NC>(T, partial + (size_t)(1 * BATCH + pb) * NC * NPTS * KNN, pi,
                tix, tiy, tiz, tix * tix + tiy * tiy + tiz * tiz, jt, dst, tcov);

  float sdot = 0.f;
#pragma unroll
  for (int k = 0; k < KNN; ++k) {
    const float ax = P[3 * jp[k]] - pix, ay = P[3 * jp[k] + 1] - piy, az = P[3 * jp[k] + 2] - piz;
    const float bx2 = T[3 * jt[k]] - tix, by2 = T[3 * jt[k] + 1] - tiy, bz2 = T[3 * jt[k] + 2] - tiz;
    const float ai = 1.0f / fmaxf(sqrtf(ax * ax + ay * ay + az * az), EPS_F);
    const float bi = 1.0f / fmaxf(sqrtf(bx2 * bx2 + by2 * by2 + bz2 * bz2), EPS_F);
    sdot += (ax * bx2 + ay * by2 + az * bz2) * (ai * bi);
  }

  const float densp = dsp * (1.0f / KNN);
  const float denst = dst * (1.0f / KNN);
  float e = (densp - denst) * (densp - denst);
  float cfro;
  {
    const float dxx = (pcov[0] - tcov[0]) * (1.0f / KNN);
    const float dyy = (pcov[1] - tcov[1]) * (1.0f / KNN);
    const float dzz = (pcov[2] - tcov[2]) * (1.0f / KNN);
    const float dxy = (pcov[3] - tcov[3]) * (1.0f / KNN);
    const float dxz = (pcov[4] - tcov[4]) * (1.0f / KNN);
    const float dyz = (pcov[5] - tcov[5]) * (1.0f / KNN);
    cfro = sqrtf(dxx * dxx + dyy * dyy + dzz * dzz
                 + 2.0f * (dxy * dxy + dxz * dxz + dyz * dyz));
  }
  float s = sdot;

  // block reduce (4 waves)
#pragma unroll
  for (int off = 32; off > 0; off >>= 1) {
    e    += __shfl_down(e, off);
    s    += __shfl_down(s, off);
    cfro += __shfl_down(cfro, off);
  }
  const int w = tid >> 6;
  if ((tid & 63) == 0) { red[w] = e; red[4 + w] = s; red[8 + w] = cfro; }
  __syncthreads();
  if (tid == 0) {
    sums[slice]       = (double)(red[0] + red[1] + red[2] + red[3]);
    sums[64 + slice]  = (double)(red[4] + red[5] + red[6] + red[7]);
    sums[128 + slice] = (double)(red[8] + red[9] + red[10] + red[11]);
    __threadfence();
    sbc[1] = atomicAdd(&counters[1], 1u) + 1u;
  }
  __syncthreads();
  if (sbc[1] == 64u) {
    __threadfence();  // acquire other slices' sums
    if (tid < 64) {
      double ee = sums[tid], ss = sums[64 + tid], cc = sums[128 + tid];
#pragma unroll
      for (int off = 32; off > 0; off >>= 1) {
        ee += __shfl_down(ee, off);
        ss += __shfl_down(ss, off);
        cc += __shfl_down(cc, off);
      }
      if (tid == 0) {
        const double BN = (double)BATCH * (double)NPTS;
        out[0] = (float)(ee / BN + 0.5 * (1.0 - ss / (BN * (double)KNN)) + 0.5 * (cc / BN));
      }
    }
  }
}

extern "C" void kernel_launch(void* const* d_in, const int* in_sizes, int n_in,
                              void* d_out, int out_size, void* d_ws, size_t ws_size,
                              hipStream_t stream) {
  const float* pred = (const float*)d_in[0];
  const float* tgt  = (const float*)d_in[1];
  uint32_t* counters = (uint32_t*)d_ws;
  double* sums = (double*)((char*)d_ws + 128);
  uint32_t* partial = (uint32_t*)((char*)d_ws + 2048);

  hipMemsetAsync(counters, 0, 16, stream);

  const size_t need16 = 2048 + (size_t)2 * BATCH * 16 * NPTS * KNN * sizeof(uint32_t);
  if (ws_size >= need16) {
    fused_t<16><<<2 * BATCH * (NPTS / 256) * 16, 256, 0, stream>>>(
        pred, tgt, partial, sums, counters, (float*)d_out);
  } else {
    fused_t<8><<<2 * BATCH * (NPTS / 256) * 8, 256, 0, stream>>>(
        pred, tgt, partial, sums, counters, (float*)d_out);
  }
}

// Round 4
// 123.507 us; speedup vs baseline: 2.8488x; 2.8488x over previous
//
#include <hip/hip_runtime.h>
#include <cstdint>
#include <cstddef>

#define NPTS   4096
#define BATCH  4
#define KNN    8
#define EPS_F  1e-12f

__device__ __forceinline__ uint32_t u32min(uint32_t a, uint32_t b) { return a < b ? a : b; }
__device__ __forceinline__ uint32_t u32max(uint32_t a, uint32_t b) { return a > b ? a : b; }
__device__ __forceinline__ unsigned long long u64min(unsigned long long a, unsigned long long b) { return a < b ? a : b; }
__device__ __forceinline__ unsigned long long u64max(unsigned long long a, unsigned long long b) { return a > b ? a : b; }

// v_med3_u32: for sorted a<=b, med3(a,b,x) == clamp(x,a,b) — one instruction.
__device__ __forceinline__ uint32_t umed3(uint32_t a, uint32_t b, uint32_t c) {
  uint32_t d;
  asm("v_med3_u32 %0, %1, %2, %3" : "=v"(d) : "v"(a), "v"(b), "v"(c));
  return d;
}

// Insert key into ascending 9-list, dropping the largest: 1 min + 8 med3,
// all 9 ops independent given (loc, key).
__device__ __forceinline__ void insert9(uint32_t loc[KNN + 1], uint32_t key) {
  uint32_t prev = loc[0];
  loc[0] = u32min(prev, key);
#pragma unroll
  for (int m = 1; m <= KNN; ++m) {
    const uint32_t cur = loc[m];
    loc[m] = umed3(prev, cur, key);
    prev = cur;
  }
}

// ---------------------------------------------------------------------------
// Kernel 1: per-(cloud,batch,point,chunk) top-9 (incl. self) by truncated key.
// Key = (float_bits(d2) & 0xFFFFF000) | j. d2>=0 -> bits monotone; ties break
// by ascending j (matches lax.top_k). Self has d2 == +0 exactly -> rank-0 in
// its own chunk; dropped there (block-uniform predicate).
// Block 0 also zeroes the accumulator/ticket region (replaces memset node).
// ---------------------------------------------------------------------------
template <int NC>
__global__ void __launch_bounds__(256, 4)
knn_partial_t(const float* __restrict__ pred, const float* __restrict__ tgt,
              uint32_t* __restrict__ partial, double* __restrict__ acc,
              uint32_t* __restrict__ ticket) {
  constexpr int CHN = NPTS / NC;
  if (blockIdx.x == 0 && threadIdx.x == 0) {
    acc[0] = 0.0; acc[1] = 0.0; acc[2] = 0.0;
    *ticket = 0u;
  }

  int bx = blockIdx.x;
  const int chunk = bx % NC; bx /= NC;
  const int ig    = bx & 15; bx >>= 4;
  const int b     = bx & 3;  bx >>= 2;
  const int cloud = bx;  // 0 = pred, 1 = target

  const float* __restrict__ pts = (cloud ? tgt : pred) + (size_t)b * NPTS * 3;
  const int tid = threadIdx.x;
  const int i = ig * 256 + tid;
  const int j0 = chunk * CHN;

  const float xix = pts[3 * i + 0];
  const float xiy = pts[3 * i + 1];
  const float xiz = pts[3 * i + 2];

  uint32_t loc[KNN + 1];
#pragma unroll
  for (int k = 0; k <= KNN; ++k) loc[k] = 0xFFFFFFFFu;

  // j0*3*4 bytes is 16B-aligned (j0 multiple of 256).
  const float4* __restrict__ c4 = (const float4*)(pts + 3 * j0);

#pragma unroll 4
  for (int t4 = 0; t4 < CHN / 4; ++t4) {
    // 3 x float4 = 4 candidates (xyz interleaved); deswizzle = register naming.
    const float4 q0 = c4[3 * t4 + 0];  // x0 y0 z0 x1
    const float4 q1 = c4[3 * t4 + 1];  // y1 z1 x2 y2
    const float4 q2 = c4[3 * t4 + 2];  // z2 x3 y3 z3
    const uint32_t jb = (uint32_t)(j0 + 4 * t4);
    {
      const float dx = xix - q0.x, dy = xiy - q0.y, dz = xiz - q0.z;
      const float d2 = fmaf(dx, dx, fmaf(dy, dy, dz * dz));
      insert9(loc, (__float_as_uint(d2) & 0xFFFFF000u) | (jb + 0u));
    }
    {
      const float dx = xix - q0.w, dy = xiy - q1.x, dz = xiz - q1.y;
      const float d2 = fmaf(dx, dx, fmaf(dy, dy, dz * dz));
      insert9(loc, (__float_as_uint(d2) & 0xFFFFF000u) | (jb + 1u));
    }
    {
      const float dx = xix - q1.z, dy = xiy - q1.w, dz = xiz - q2.x;
      const float d2 = fmaf(dx, dx, fmaf(dy, dy, dz * dz));
      insert9(loc, (__float_as_uint(d2) & 0xFFFFF000u) | (jb + 2u));
    }
    {
      const float dx = xix - q2.y, dy = xiy - q2.z, dz = xiz - q2.w;
      const float d2 = fmaf(dx, dx, fmaf(dy, dy, dz * dz));
      insert9(loc, (__float_as_uint(d2) & 0xFFFFF000u) | (jb + 3u));
    }
  }

  const bool self_chunk = ((ig * 256) / CHN) == chunk;
  uint4 o0, o1;
  if (self_chunk) {
    o0 = make_uint4(loc[1], loc[2], loc[3], loc[4]);
    o1 = make_uint4(loc[5], loc[6], loc[7], loc[8]);
  } else {
    o0 = make_uint4(loc[0], loc[1], loc[2], loc[3]);
    o1 = make_uint4(loc[4], loc[5], loc[6], loc[7]);
  }
  uint32_t* p = partial +
      ((((size_t)(cloud * BATCH + b) * NC + chunk) * NPTS) + (size_t)i) * KNN;
  *(uint4*)p = o0;
  *(uint4*)(p + 4) = o1;
}

// Streaming bitonic merge of NC sorted 8-lists, keep smallest 8.
template <int NC>
__device__ __forceinline__ void merge_list(const uint32_t* __restrict__ base, int i,
                                           uint32_t out[KNN]) {
  const uint32_t* p0 = base + (size_t)i * KNN;
  uint4 a = *(const uint4*)p0, bq = *(const uint4*)(p0 + 4);
  out[0] = a.x; out[1] = a.y; out[2] = a.z; out[3] = a.w;
  out[4] = bq.x; out[5] = bq.y; out[6] = bq.z; out[7] = bq.w;
#pragma unroll
  for (int c = 1; c < NC; ++c) {
    const uint32_t* pc = base + ((size_t)c * NPTS + (size_t)i) * KNN;
    const uint4 l0 = *(const uint4*)pc, l1 = *(const uint4*)(pc + 4);
    const uint32_t L[KNN] = {l0.x, l0.y, l0.z, l0.w, l1.x, l1.y, l1.z, l1.w};
    uint32_t t[KNN];
#pragma unroll
    for (int m = 0; m < KNN; ++m) t[m] = u32min(out[m], L[KNN - 1 - m]);
    if (c != NC - 1) {
#define CEU(x, y) { uint32_t lo = u32min(t[x], t[y]); uint32_t hi = u32max(t[x], t[y]); t[x] = lo; t[y] = hi; }
      CEU(0,4) CEU(1,5) CEU(2,6) CEU(3,7)
      CEU(0,2) CEU(1,3) CEU(4,6) CEU(5,7)
      CEU(0,1) CEU(2,3) CEU(4,5) CEU(6,7)
#undef CEU
    }
#pragma unroll
    for (int m = 0; m < KNN; ++m) out[m] = t[m];
  }
}

// Batcher odd-even mergesort, 8 elements, 19 compare-exchanges.
__device__ __forceinline__ void sort8(unsigned long long s[8]) {
#define CE(a, b) { unsigned long long lo = u64min(s[a], s[b]); \
                   unsigned long long hi = u64max(s[a], s[b]); s[a] = lo; s[b] = hi; }
  CE(0,1) CE(2,3) CE(0,2) CE(1,3) CE(1,2)
  CE(4,5) CE(6,7) CE(4,6) CE(5,7) CE(5,6)
  CE(0,4) CE(1,5) CE(2,6) CE(3,7)
  CE(2,4) CE(3,5)
  CE(1,2) CE(3,4) CE(5,6)
#undef CE
}

// ---------------------------------------------------------------------------
// Kernel 2 (one wave per block): merge partials, recompute exact distances
// (reference's sq_i + sq_j - 2*dot), re-sort by (exact dist, idx), loss terms,
// wave-reduce, atomicAdd; last block (ticket) finalizes and writes d_out.
// ---------------------------------------------------------------------------
template <int NC>
__global__ void __launch_bounds__(64)
loss_t(const float* __restrict__ pred, const float* __restrict__ tgt,
       const uint32_t* __restrict__ partial, double* __restrict__ acc,
       uint32_t* __restrict__ ticket, float* __restrict__ out) {
  const int p = blockIdx.x * 64 + threadIdx.x;   // 0 .. 16383
  const int b = p >> 12;
  const int i = p & (NPTS - 1);

  const float* __restrict__ P = pred + (size_t)b * NPTS * 3;
  const float* __restrict__ T = tgt  + (size_t)b * NPTS * 3;

  uint32_t mp[KNN], mt[KNN];
  merge_list<NC>(partial + (size_t)(0 * BATCH + b) * NC * NPTS * KNN, i, mp);
  merge_list<NC>(partial + (size_t)(1 * BATCH + b) * NC * NPTS * KNN, i, mt);

  const float pix = P[3 * i], piy = P[3 * i + 1], piz = P[3 * i + 2];
  const float tix = T[3 * i], tiy = T[3 * i + 1], tiz = T[3 * i + 2];
  const float sqp = pix * pix + piy * piy + piz * piz;
  const float sqt = tix * tix + tiy * tiy + tiz * tiz;

  unsigned long long kp[KNN], kt[KNN];
#pragma unroll
  for (int k = 0; k < KNN; ++k) {
    {
      const int j = (int)(mp[k] & 0xFFFu);
      const float x = P[3 * j], y = P[3 * j + 1], z = P[3 * j + 2];
      const float d2 = sqp + (x * x + y * y + z * z)
                       - 2.0f * (pix * x + piy * y + piz * z);
      const float dist = sqrtf(fmaxf(d2, EPS_F));
      kp[k] = ((unsigned long long)__float_as_uint(dist) << 12) | (unsigned long long)j;
    }
    {
      const int j = (int)(mt[k] & 0xFFFu);
      const float x = T[3 * j], y = T[3 * j + 1], z = T[3 * j + 2];
      const float d2 = sqt + (x * x + y * y + z * z)
                       - 2.0f * (tix * x + tiy * y + tiz * z);
      const float dist = sqrtf(fmaxf(d2, EPS_F));
      kt[k] = ((unsigned long long)__float_as_uint(dist) << 12) | (unsigned long long)j;
    }
  }
  sort8(kp);
  sort8(kt);

  float dsp = 0.f, dst = 0.f, sdot = 0.f;
  float pcov[6] = {0, 0, 0, 0, 0, 0}, tcov[6] = {0, 0, 0, 0, 0, 0};
#pragma unroll
  for (int k = 0; k < KNN; ++k) {
    const int jp = (int)(kp[k] & 0xFFFu);
    dsp += __uint_as_float((uint32_t)(kp[k] >> 12));
    const float ax = P[3 * jp] - pix, ay = P[3 * jp + 1] - piy, az = P[3 * jp + 2] - piz;
    const float ai = 1.0f / fmaxf(sqrtf(ax * ax + ay * ay + az * az), EPS_F);
    pcov[0] += ax * ax; pcov[1] += ay * ay; pcov[2] += az * az;
    pcov[3] += ax * ay; pcov[4] += ax * az; pcov[5] += ay * az;

    const int jt = (int)(kt[k] & 0xFFFu);
    dst += __uint_as_float((uint32_t)(kt[k] >> 12));
    const float bx = T[3 * jt] - tix, by = T[3 * jt + 1] - tiy, bz = T[3 * jt + 2] - tiz;
    const float bi = 1.0f / fmaxf(sqrtf(bx * bx + by * by + bz * bz), EPS_F);
    tcov[0] += bx * bx; tcov[1] += by * by; tcov[2] += bz * bz;
    tcov[3] += bx * by; tcov[4] += bx * bz; tcov[5] += by * bz;

    sdot += (ax * bx + ay * by + az * bz) * (ai * bi);
  }

  const float densp = dsp * (1.0f / KNN);
  const float denst = dst * (1.0f / KNN);
  float e = (densp - denst) * (densp - denst);

  const float dxx = (pcov[0] - tcov[0]) * (1.0f / KNN);
  const float dyy = (pcov[1] - tcov[1]) * (1.0f / KNN);
  const float dzz = (pcov[2] - tcov[2]) * (1.0f / KNN);
  const float dxy = (pcov[3] - tcov[3]) * (1.0f / KNN);
  const float dxz = (pcov[4] - tcov[4]) * (1.0f / KNN);
  const float dyz = (pcov[5] - tcov[5]) * (1.0f / KNN);
  float cfro = sqrtf(dxx * dxx + dyy * dyy + dzz * dzz
                     + 2.0f * (dxy * dxy + dxz * dxz + dyz * dyz));
  float s = sdot;

#pragma unroll
  for (int off = 32; off > 0; off >>= 1) {
    e    += __shfl_down(e, off);
    s    += __shfl_down(s, off);
    cfro += __shfl_down(cfro, off);
  }
  if (threadIdx.x == 0) {
    atomicAdd(&acc[0], (double)e);
    atomicAdd(&acc[1], (double)s);
    atomicAdd(&acc[2], (double)cfro);
    __threadfence();
    const unsigned rank = atomicAdd(ticket, 1u) + 1u;
    if (rank == (unsigned)((BATCH * NPTS) / 64)) {
      __threadfence();
      const double ee = __hip_atomic_load(&acc[0], __ATOMIC_RELAXED, __HIP_MEMORY_SCOPE_AGENT);
      const double ss = __hip_atomic_load(&acc[1], __ATOMIC_RELAXED, __HIP_MEMORY_SCOPE_AGENT);
      const double cc = __hip_atomic_load(&acc[2], __ATOMIC_RELAXED, __HIP_MEMORY_SCOPE_AGENT);
      const double BN = (double)BATCH * (double)NPTS;
      out[0] = (float)(ee / BN + 0.5 * (1.0 - ss / (BN * (double)KNN)) + 0.5 * (cc / BN));
    }
  }
}

extern "C" void kernel_launch(void* const* d_in, const int* in_sizes, int n_in,
                              void* d_out, int out_size, void* d_ws, size_t ws_size,
                              hipStream_t stream) {
  const float* pred = (const float*)d_in[0];
  const float* tgt  = (const float*)d_in[1];
  double* acc = (double*)d_ws;                       // 3 doubles @ 0
  uint32_t* ticket = (uint32_t*)((char*)d_ws + 64);  // 1 u32 @ 64
  uint32_t* partial = (uint32_t*)((char*)d_ws + 4096);

  const size_t need16 = 4096 + (size_t)2 * BATCH * 16 * NPTS * KNN * sizeof(uint32_t);
  if (ws_size >= need16) {
    knn_partial_t<16><<<2 * BATCH * (NPTS / 256) * 16, 256, 0, stream>>>(
        pred, tgt, partial, acc, ticket);
    loss_t<16><<<(BATCH * NPTS) / 64, 64, 0, stream>>>(
        pred, tgt, partial, acc, ticket, (float*)d_out);
  } else {
    knn_partial_t<8><<<2 * BATCH * (NPTS / 256) * 8, 256, 0, stream>>>(
        pred, tgt, partial, acc, ticket);
    loss_t<8><<<(BATCH * NPTS) / 64, 64, 0, stream>>>(
        pred, tgt, partial, acc, ticket, (float*)d_out);
  }
}